// Round 2
// baseline (900.262 us; speedup 1.0000x reference)
//
#include <hip/hip_runtime.h>
#include <math.h>

typedef __bf16 bf16x8 __attribute__((ext_vector_type(8)));
typedef float  f32x4  __attribute__((ext_vector_type(4)));
typedef _Float16 f16x4 __attribute__((ext_vector_type(4)));

#define GLOAD16(g, l) __builtin_amdgcn_global_load_lds( \
    (const __attribute__((address_space(1))) void*)(g), \
    (__attribute__((address_space(3))) void*)(l), 16, 0, 0)

// ---------------- fp32 -> bf16 convert ----------------
__global__ __launch_bounds__(256) void cvt_bf16(const float* __restrict__ in,
                                                __bf16* __restrict__ out)
{
    const int i = (blockIdx.x * 256 + threadIdx.x) * 4;
    float4 f = *(const float4*)(in + i);
    out[i + 0] = (__bf16)f.x; out[i + 1] = (__bf16)f.y;
    out[i + 2] = (__bf16)f.z; out[i + 3] = (__bf16)f.w;
}

// ---------------- transpose + fp32->bf16: out[c][r] = in[r][c] ----------------
__global__ __launch_bounds__(256) void transpose_cvt(
    const float* __restrict__ in, __bf16* __restrict__ out,
    int C, int outLd, long inZ, int zdiv, long outZ1, long outZ2)
{
    __shared__ float t[32][33];
    const int z = blockIdx.z, z1 = z / zdiv, z2 = z % zdiv;
    in  += (long)z * inZ;
    out += z1 * outZ1 + z2 * outZ2;
    const int c0 = blockIdx.x * 32, r0 = blockIdx.y * 32;
    const int tx = threadIdx.x, ty = threadIdx.y;
    #pragma unroll
    for (int i = 0; i < 32; i += 8)
        t[ty + i][tx] = in[(long)(r0 + ty + i) * C + c0 + tx];
    __syncthreads();
    #pragma unroll
    for (int i = 0; i < 32; i += 8)
        out[(long)(c0 + ty + i) * outLd + r0 + tx] = (__bf16)t[tx][ty + i];
}

// ---------------- m97-style MFMA GEMM (small shapes): C = A * Bt^T [+resid] ----
__global__ __launch_bounds__(256) void mfma_gemm(
    const __bf16* __restrict__ A, const __bf16* __restrict__ Bt,
    int lda, int ldb, int K,
    float* __restrict__ outF, int ldf,
    __bf16* __restrict__ outB, int ldo,
    const float* __restrict__ resid, int ldr)
{
    __shared__ __bf16 As[128 * 32];   // [m][k] unpadded (global_load_lds layout)
    __shared__ __bf16 Bs[128 * 32];   // [n][k]

    // T1 bijective XCD swizzle (all grids are multiples of 8 blocks)
    int lid = blockIdx.y * gridDim.x + blockIdx.x;
    const int nwg = gridDim.x * gridDim.y;
    lid = (lid & 7) * (nwg >> 3) + (lid >> 3);
    const int m0 = (lid / gridDim.x) * 128, n0 = (lid % gridDim.x) * 128;

    const int t = threadIdx.x, w = t >> 6, ln = t & 63;
    const int r = ln & 15, q = ln >> 4;
    const int wm = (w >> 1) * 64, wn = (w & 1) * 64;

    f32x4 acc[4][4];
    #pragma unroll
    for (int i = 0; i < 4; ++i)
        #pragma unroll
        for (int j = 0; j < 4; ++j)
            acc[i][j] = f32x4{0.f, 0.f, 0.f, 0.f};

    const int srow = ln >> 2, scol = (ln & 3) * 8; // within 16-row chunk

    for (int k0 = 0; k0 < K; k0 += 32) {
        #pragma unroll
        for (int c = 0; c < 2; ++c) {
            const int ch = w + c * 4;               // 8 chunks of 16 rows
            const __bf16* ga = A  + (long)(m0 + ch * 16 + srow) * lda + k0 + scol;
            GLOAD16(ga, &As[ch * 512]);
            const __bf16* gb = Bt + (long)(n0 + ch * 16 + srow) * ldb + k0 + scol;
            GLOAD16(gb, &Bs[ch * 512]);
        }
        __syncthreads();
        bf16x8 af[4], bv[4];
        #pragma unroll
        for (int i = 0; i < 4; ++i) af[i] = *(const bf16x8*)&As[(wm + i * 16 + r) * 32 + q * 8];
        #pragma unroll
        for (int i = 0; i < 4; ++i) bv[i] = *(const bf16x8*)&Bs[(wn + i * 16 + r) * 32 + q * 8];
        #pragma unroll
        for (int i = 0; i < 4; ++i)
            #pragma unroll
            for (int j = 0; j < 4; ++j)
                acc[i][j] = __builtin_amdgcn_mfma_f32_16x16x32_bf16(af[i], bv[j], acc[i][j], 0, 0, 0);
        __syncthreads();
    }

    #pragma unroll
    for (int i = 0; i < 4; ++i) {
        #pragma unroll
        for (int j = 0; j < 4; ++j) {
            #pragma unroll
            for (int g = 0; g < 4; ++g) {
                const int m = m0 + wm + i * 16 + q * 4 + g;
                const int n = n0 + wn + j * 16 + r;
                float v = acc[i][j][g];
                if (resid) v += resid[(long)m * ldr + n];
                if (outF)  outF[(long)m * ldf + n] = v;
                if (outB)  outB[(long)m * ldo + n] = (__bf16)v;
            }
        }
    }
}

// ---------------- 256x256 deep-pipelined GEMM for QKV (T1+T2+T3+T4+T5) -------
// A [4096][1024] bf16, Bt [3072][1024] bf16. Grid 192 blocks x 512 thr (8 waves).
// Ring of 4 K=32 slices per matrix (128 KiB dynamic LDS). Slice j staged 3 steps
// ahead; per step: vmcnt(8) -> barrier -> 12x ds_read_b128 (XOR-swizzled) ->
// issue 4 prefetch global_load_lds -> 32 MFMA (setprio). vmcnt never 0 in loop.
// Swizzle (both-sides, rule #21): phys 16B-granule = logical ^ ((row>>2)&3);
// write side pre-swizzles the GLOBAL source, LDS dest stays linear.
__device__ __forceinline__ void stage_slice(
    const __bf16* __restrict__ src, int ld, int row0, int k0,
    __bf16* ring, int w, int ln)
{
    #pragma unroll
    for (int c = 0; c < 2; ++c) {
        const int L = 2 * w + c;               // 16 rows (64B each) per load
        const int row = L * 16 + (ln >> 2);
        const int lg = (ln & 3) ^ ((row >> 2) & 3);
        const __bf16* g = src + (long)(row0 + row) * ld + k0 + lg * 8;
        GLOAD16(g, ring + L * 512);            // wave-uniform LDS base
    }
}

__global__ __launch_bounds__(512, 1) void gemm256(
    const __bf16* __restrict__ A, const __bf16* __restrict__ Bt,
    int lda, int ldb, int K,
    __bf16* __restrict__ outB, __bf16* __restrict__ vt)
{
    extern __shared__ char smem[];
    __bf16* As = (__bf16*)smem;                // 4 slots x 256x32 (16 KB)
    __bf16* Bs = (__bf16*)(smem + 65536);

    // T1: 2D chunk per XCD (4mt x 6nt per chunk; 16x12 tile grid)
    const int bid = blockIdx.x;
    const int xcd = bid & 7, idx = bid >> 3;
    const int mt = (xcd & 3) * 4 + (idx & 3);
    const int nt = (xcd >> 2) * 6 + (idx >> 2);
    const int m0 = mt * 256, n0 = nt * 256;

    const int t = threadIdx.x, w = t >> 6, ln = t & 63;
    const int r = ln & 15, q = ln >> 4;
    const int wm = w >> 2, wn = w & 3;         // 2 x 4 wave grid, 128x64 each

    f32x4 acc[8][4];
    #pragma unroll
    for (int i = 0; i < 8; ++i)
        #pragma unroll
        for (int jf = 0; jf < 4; ++jf)
            acc[i][jf] = f32x4{0.f, 0.f, 0.f, 0.f};

    const int nk = K >> 5;                     // 32 slices
    #pragma unroll
    for (int j = 0; j < 3; ++j) {              // prologue: slices 0..2
        stage_slice(A,  lda, m0, j * 32, As + j * 8192, w, ln);
        stage_slice(Bt, ldb, n0, j * 32, Bs + j * 8192, w, ln);
    }

#define GSTEP(J, VM) { \
    asm volatile("s_waitcnt vmcnt(" #VM ")" ::: "memory"); \
    __builtin_amdgcn_s_barrier(); \
    __builtin_amdgcn_sched_barrier(0); \
    const __bf16* as_ = As + ((J) & 3) * 8192; \
    const __bf16* bs_ = Bs + ((J) & 3) * 8192; \
    bf16x8 af[8], bv[4]; \
    _Pragma("unroll") \
    for (int i = 0; i < 8; ++i) { \
        const int row = wm * 128 + i * 16 + r; \
        af[i] = *(const bf16x8*)&as_[row * 32 + ((q ^ ((row >> 2) & 3)) << 3)]; \
    } \
    _Pragma("unroll") \
    for (int jf = 0; jf < 4; ++jf) { \
        const int row = wn * 64 + jf * 16 + r; \
        bv[jf] = *(const bf16x8*)&bs_[row * 32 + ((q ^ ((row >> 2) & 3)) << 3)]; \
    } \
    if ((J) + 3 < nk) { \
        stage_slice(A,  lda, m0, ((J) + 3) * 32, As + (((J) + 3) & 3) * 8192, w, ln); \
        stage_slice(Bt, ldb, n0, ((J) + 3) * 32, Bs + (((J) + 3) & 3) * 8192, w, ln); \
    } \
    __builtin_amdgcn_s_setprio(1); \
    _Pragma("unroll") \
    for (int i = 0; i < 8; ++i) \
        _Pragma("unroll") \
        for (int jf = 0; jf < 4; ++jf) \
            acc[i][jf] = __builtin_amdgcn_mfma_f32_16x16x32_bf16(af[i], bv[jf], acc[i][jf], 0, 0, 0); \
    __builtin_amdgcn_s_setprio(0); \
}

    for (int j = 0; j < nk - 2; ++j) GSTEP(j, 8);
    GSTEP(nk - 2, 4);
    GSTEP(nk - 1, 0);
#undef GSTEP

    // epilogue: whole 256-col block tile is either QK (nt<8) or V (nt>=8)
    const bool isV = (nt >= 8);
    #pragma unroll
    for (int i = 0; i < 8; ++i) {
        #pragma unroll
        for (int jf = 0; jf < 4; ++jf) {
            #pragma unroll
            for (int g = 0; g < 4; ++g) {
                const int row = m0 + wm * 128 + i * 16 + q * 4 + g;
                const int col = n0 + wn * 64 + jf * 16 + r;
                const __bf16 v = (__bf16)acc[i][jf][g];
                if (isV) {                      // V -> [b,h,p,s]
                    const int p = col - 2048, h = p >> 7, pp = p & 127;
                    const int b = row >> 9, s = row & 511;
                    vt[(((long)(b * 8 + h)) * 128 + pp) * 512 + s] = v;
                } else {
                    outB[(long)row * 2048 + col] = v;
                }
            }
        }
    }
}

// ---------------- fused causal attention: one-pass, S-resident ----------------
__global__ __launch_bounds__(256, 3) void flash2(
    const __bf16* __restrict__ QK, const __bf16* __restrict__ Vt,
    float* __restrict__ atts, __bf16* __restrict__ comb)
{
    const int f = blockIdx.x;
    const int bh = (f & 7) * 8 + ((f >> 3) & 7);
    const int qt = f >> 6;                 // q-tile of 64 rows, 0..7
    const int b = bh >> 3, h = bh & 7;
    const int nkt = (qt >> 1) + 1;         // K tiles of 128 cols needed
    const float rs = 0.08838834764831845f;

    __shared__ __bf16 KVs[128 * 136];      // K in phase 1, V in phase 2
    __shared__ __bf16 Ps[4 * 16 * 136];    // per-wave P scratch (bf16)

    const int t = threadIdx.x, w = t >> 6, ln = t & 63;
    const int r = ln & 15, q = ln >> 4;

    const long qrow = (long)(b * 512 + qt * 64 + w * 16 + r);
    bf16x8 Qf[4];
    #pragma unroll
    for (int kp = 0; kp < 4; ++kp)
        Qf[kp] = *(const bf16x8*)(QK + qrow * 2048 + h * 128 + kp * 32 + q * 8);

    f16x4 E16[4][8];                       // exp(S*rs-3), packed f16, whole row
    float L[4] = {0.f, 0.f, 0.f, 0.f};

    #pragma unroll
    for (int kt = 0; kt < 4; ++kt) {
        if (kt < nkt) {
            __syncthreads();
            const __bf16* ksrc = QK + ((long)(b * 512 + kt * 128)) * 2048 + 1024 + h * 128;
            #pragma unroll
            for (int c0 = 0; c0 < 8; ++c0) {
                const int c = c0 * 256 + t;
                const int row = c >> 4, col = (c & 15) * 8;
                *(bf16x8*)&KVs[row * 136 + col] = *(const bf16x8*)(ksrc + (long)row * 2048 + col);
            }
            __syncthreads();

            #pragma unroll
            for (int nb = 0; nb < 8; ++nb) {
                f32x4 s = f32x4{0.f, 0.f, 0.f, 0.f};
                #pragma unroll
                for (int kp = 0; kp < 4; ++kp) {
                    bf16x8 bv = *(const bf16x8*)&KVs[(nb * 16 + r) * 136 + kp * 32 + q * 8];
                    s = __builtin_amdgcn_mfma_f32_16x16x32_bf16(Qf[kp], bv, s, 0, 0, 0);
                }
                const int kc = kt * 128 + nb * 16 + r;
                f16x4 e;
                #pragma unroll
                for (int g = 0; g < 4; ++g) {
                    float ev = __expf(s[g] * rs - 3.0f);
                    if (kt == nkt - 1) {
                        const int qr = qt * 64 + w * 16 + q * 4 + g;
                        if (kc > qr) ev = 0.f;
                    }
                    L[g] += ev;
                    e[g] = (_Float16)ev;
                }
                E16[kt][nb] = e;
            }
        }
    }

    float linv[4];
    #pragma unroll
    for (int g = 0; g < 4; ++g) {
        float Lg = L[g];
        #pragma unroll
        for (int s = 1; s < 16; s <<= 1) Lg += __shfl_xor(Lg, s);
        linv[g] = 1.0f / Lg;
    }

    f32x4 O[8];
    #pragma unroll
    for (int pb = 0; pb < 8; ++pb) O[pb] = f32x4{0.f, 0.f, 0.f, 0.f};

    float* abase = atts + (long)bh * 262144 + (long)(qt * 64 + w * 16) * 512;
    __bf16* psw = &Ps[w * 16 * 136];

    #pragma unroll
    for (int kt = 0; kt < 4; ++kt) {
        if (kt < nkt) {
            __syncthreads();
            const __bf16* vsrc = Vt + (long)bh * 65536 + kt * 128;
            #pragma unroll
            for (int c0 = 0; c0 < 8; ++c0) {
                const int c = c0 * 256 + t;
                const int row = c >> 4, col = (c & 15) * 8;
                *(bf16x8*)&KVs[row * 136 + col] = *(const bf16x8*)(vsrc + (long)row * 512 + col);
            }
            __syncthreads();

            #pragma unroll
            for (int nb = 0; nb < 8; ++nb) {
                f16x4 e = E16[kt][nb];
                #pragma unroll
                for (int g = 0; g < 4; ++g) {
                    float p = (float)e[g] * linv[g];
                    abase[(long)(q * 4 + g) * 512 + kt * 128 + nb * 16 + r] = p;
                    psw[(q * 4 + g) * 136 + nb * 16 + r] = (__bf16)p;
                }
            }
            bf16x8 Pf[4];
            #pragma unroll
            for (int kp = 0; kp < 4; ++kp)
                Pf[kp] = *(const bf16x8*)&psw[r * 136 + kp * 32 + q * 8];
            #pragma unroll
            for (int pb = 0; pb < 8; ++pb) {
                #pragma unroll
                for (int kp = 0; kp < 4; ++kp) {
                    bf16x8 bv = *(const bf16x8*)&KVs[(pb * 16 + r) * 136 + kp * 32 + q * 8];
                    O[pb] = __builtin_amdgcn_mfma_f32_16x16x32_bf16(Pf[kp], bv, O[pb], 0, 0, 0);
                }
            }
        }
    }

    {
        float* zbase = atts + (long)bh * 262144 + (long)(qt * 64) * 512;
        float4 z4 = {0.f, 0.f, 0.f, 0.f};
        for (int ktz = nkt; ktz < 4; ++ktz) {
            #pragma unroll
            for (int c0 = 0; c0 < 8; ++c0) {
                const int c = c0 * 256 + t;
                const int row = c >> 5, col = (c & 31) * 4;
                *(float4*)&zbase[(long)row * 512 + ktz * 128 + col] = z4;
            }
        }
    }

    const long crow = (long)(b * 512 + qt * 64 + w * 16);
    #pragma unroll
    for (int pb = 0; pb < 8; ++pb)
        #pragma unroll
        for (int g = 0; g < 4; ++g)
            comb[(crow + q * 4 + g) * 1024 + h * 128 + pb * 16 + r] = (__bf16)O[pb][g];
}

extern "C" void kernel_launch(void* const* d_in, const int* in_sizes, int n_in,
                              void* d_out, int out_size, void* d_ws, size_t ws_size,
                              hipStream_t stream)
{
    const float* tokens = (const float*)d_in[0];
    const float* embedW = (const float*)d_in[2];
    const float* unembW = (const float*)d_in[3];
    const float* wq     = (const float*)d_in[4];
    const float* wk     = (const float*)d_in[5];
    const float* wv     = (const float*)d_in[6];
    const float* wo     = (const float*)d_in[7];

    float* out       = (float*)d_out;
    float* logits_o  = out;                 // [8,512,256]
    float* atts_o    = out + 1048576L;      // [4,64,512,512]
    float* streams_o = atts_o + 67108864L;  // [5,4096,1024]

    __bf16* embedWt   = (__bf16*)d_ws;            // [1024][256]
    __bf16* unembWt   = embedWt + 262144;         // [256][1024]
    __bf16* WtAll     = unembWt + 262144;         // [L][3072][1024]
    __bf16* WotAll    = WtAll + 12582912;         // [L][1024][1024]
    __bf16* tokens_bf = WotAll + 4194304;         // [4096][256]
    __bf16* stream_bf = tokens_bf + 1048576;      // [4096][1024]
    __bf16* QKbuf     = stream_bf + 4194304;      // [4096][2048]
    __bf16* Vt        = QKbuf + 8388608;          // [64][128][512]
    __bf16* comb      = Vt + 4194304;             // [4096][1024]

    const dim3 T(32, 8), G1(256);

    // 128 KiB dynamic LDS for gemm256
    hipFuncSetAttribute((const void*)gemm256,
                        hipFuncAttributeMaxDynamicSharedMemorySize, 131072);

    // prep: token convert + all weight transposes (no interdependencies)
    cvt_bf16<<<dim3(1024), G1, 0, stream>>>(tokens, tokens_bf);
    transpose_cvt<<<dim3(32, 8, 1), T, 0, stream>>>(embedW, embedWt, 1024, 256, 0, 1, 0, 0);
    transpose_cvt<<<dim3(8, 32, 1), T, 0, stream>>>(unembW, unembWt, 256, 1024, 0, 1, 0, 0);
    transpose_cvt<<<dim3(4, 32, 32), T, 0, stream>>>(wq, WtAll,           128, 1024, 131072, 8, 3145728, 131072);
    transpose_cvt<<<dim3(4, 32, 32), T, 0, stream>>>(wk, WtAll + 1048576, 128, 1024, 131072, 8, 3145728, 131072);
    transpose_cvt<<<dim3(4, 32, 32), T, 0, stream>>>(wv, WtAll + 2097152, 128, 1024, 131072, 8, 3145728, 131072);
    transpose_cvt<<<dim3(32, 32, 4), T, 0, stream>>>(wo, WotAll, 1024, 1024, 1048576, 1, 1048576, 0);

    // embed: [4096,256] x [256->1024]
    mfma_gemm<<<dim3(8, 32), G1, 0, stream>>>(
        tokens_bf, embedWt, 256, 256, 256,
        streams_o, 1024, stream_bf, 1024, nullptr, 0);

    for (int l = 0; l < 4; ++l) {
        float* st  = streams_o + (long)l * 4194304;
        float* stn = st + 4194304;
        float* attl = atts_o + (long)l * 16777216;

        // QKV: [4096,1024] x [1024->3072]; q,k -> QKbuf, v -> Vt (transposed)
        gemm256<<<dim3(192), dim3(512), 131072, stream>>>(
            stream_bf, WtAll + (long)l * 3145728, 1024, 1024, 1024,
            QKbuf, Vt);

        flash2<<<dim3(512), G1, 0, stream>>>(QKbuf, Vt, attl, comb);

        // stream_{l+1} = stream_l + comb @ wo
        mfma_gemm<<<dim3(8, 32), G1, 0, stream>>>(
            comb, WotAll + (long)l * 1048576, 1024, 1024, 1024,
            stn, 1024, stream_bf, 1024, st, 1024);
    }

    // logits = stream_L @ unembW
    mfma_gemm<<<dim3(2, 32), G1, 0, stream>>>(
        stream_bf, unembWt, 1024, 1024, 1024,
        logits_o, 256, nullptr, 0, nullptr, 0);
}

// Round 4
// 876.571 us; speedup vs baseline: 1.0270x; 1.0270x over previous
//
#include <hip/hip_runtime.h>
#include <math.h>

typedef __bf16 bf16x8 __attribute__((ext_vector_type(8)));
typedef __bf16 bf16x4 __attribute__((ext_vector_type(4)));
typedef float  f32x4  __attribute__((ext_vector_type(4)));
typedef _Float16 f16x4 __attribute__((ext_vector_type(4)));

#define GLOAD16(g, l) __builtin_amdgcn_global_load_lds( \
    (const __attribute__((address_space(1))) void*)(g), \
    (__attribute__((address_space(3))) void*)(l), 16, 0, 0)

// ---------------- fp32 -> bf16 convert ----------------
__global__ __launch_bounds__(256) void cvt_bf16(const float* __restrict__ in,
                                                __bf16* __restrict__ out)
{
    const int i = (blockIdx.x * 256 + threadIdx.x) * 4;
    float4 f = *(const float4*)(in + i);
    out[i + 0] = (__bf16)f.x; out[i + 1] = (__bf16)f.y;
    out[i + 2] = (__bf16)f.z; out[i + 3] = (__bf16)f.w;
}

// ---------------- transpose + fp32->bf16: out[c][r] = in[r][c] ----------------
__global__ __launch_bounds__(256) void transpose_cvt(
    const float* __restrict__ in, __bf16* __restrict__ out,
    int C, int outLd, long inZ, int zdiv, long outZ1, long outZ2)
{
    __shared__ float t[32][33];
    const int z = blockIdx.z, z1 = z / zdiv, z2 = z % zdiv;
    in  += (long)z * inZ;
    out += z1 * outZ1 + z2 * outZ2;
    const int c0 = blockIdx.x * 32, r0 = blockIdx.y * 32;
    const int tx = threadIdx.x, ty = threadIdx.y;
    #pragma unroll
    for (int i = 0; i < 32; i += 8)
        t[ty + i][tx] = in[(long)(r0 + ty + i) * C + c0 + tx];
    __syncthreads();
    #pragma unroll
    for (int i = 0; i < 32; i += 8)
        out[(long)(c0 + ty + i) * outLd + r0 + tx] = (__bf16)t[tx][ty + i];
}

// ---------------- fused wq/wk/wv transpose (one launch) ----------------
__global__ __launch_bounds__(256) void transpose_qkv(
    const float* __restrict__ wq, const float* __restrict__ wk,
    const float* __restrict__ wv, __bf16* __restrict__ out)
{
    __shared__ float tl[32][33];
    const int z = blockIdx.z;                  // 0..95
    const int m = z >> 5, zz = z & 31;         // m: 0=q,1=k,2=v; zz = l*8+h
    const float* in = (m == 0 ? wq : m == 1 ? wk : wv) + (long)zz * 131072;
    __bf16* o = out + (long)m * 1048576 + (long)(zz >> 3) * 3145728
                    + (long)(zz & 7) * 131072;
    const int c0 = blockIdx.x * 32, r0 = blockIdx.y * 32;  // C=128, rows=1024
    const int tx = threadIdx.x, ty = threadIdx.y;
    #pragma unroll
    for (int i = 0; i < 32; i += 8)
        tl[ty + i][tx] = in[(long)(r0 + ty + i) * 128 + c0 + tx];
    __syncthreads();
    #pragma unroll
    for (int i = 0; i < 32; i += 8)
        o[(long)(c0 + ty + i) * 1024 + r0 + tx] = (__bf16)tl[tx][ty + i];
}

// ---------------- m97-style MFMA GEMM: C = A * Bt^T [+resid] ----------------
// A [M,K] bf16, Bt [N,K] bf16. Tile 128x128, BK=32, 4 waves, global_load_lds.
// T1 bijective XCD swizzle (all grids are multiples of 8 blocks).
__global__ __launch_bounds__(256) void mfma_gemm(
    const __bf16* __restrict__ A, const __bf16* __restrict__ Bt,
    int lda, int ldb, int K,
    float* __restrict__ outF, int ldf,
    __bf16* __restrict__ outB, int ldo,
    __bf16* __restrict__ vt,
    const float* __restrict__ resid, int ldr)
{
    __shared__ __bf16 As[128 * 32];   // [m][k] unpadded (global_load_lds layout)
    __shared__ __bf16 Bs[128 * 32];   // [n][k]

    int lid = blockIdx.y * gridDim.x + blockIdx.x;
    const int nwg = gridDim.x * gridDim.y;
    lid = (lid & 7) * (nwg >> 3) + (lid >> 3);
    const int m0 = (lid / gridDim.x) * 128, n0 = (lid % gridDim.x) * 128;

    const int t = threadIdx.x, w = t >> 6, ln = t & 63;
    const int r = ln & 15, q = ln >> 4;
    const int wm = (w >> 1) * 64, wn = (w & 1) * 64;

    f32x4 acc[4][4];
    #pragma unroll
    for (int i = 0; i < 4; ++i)
        #pragma unroll
        for (int j = 0; j < 4; ++j)
            acc[i][j] = f32x4{0.f, 0.f, 0.f, 0.f};

    const int srow = ln >> 2, scol = (ln & 3) * 8; // within 16-row chunk

    for (int k0 = 0; k0 < K; k0 += 32) {
        #pragma unroll
        for (int c = 0; c < 2; ++c) {
            const int ch = w + c * 4;               // 8 chunks of 16 rows
            const __bf16* ga = A  + (long)(m0 + ch * 16 + srow) * lda + k0 + scol;
            GLOAD16(ga, &As[ch * 512]);
            const __bf16* gb = Bt + (long)(n0 + ch * 16 + srow) * ldb + k0 + scol;
            GLOAD16(gb, &Bs[ch * 512]);
        }
        __syncthreads();
        bf16x8 af[4], bv[4];
        #pragma unroll
        for (int i = 0; i < 4; ++i) af[i] = *(const bf16x8*)&As[(wm + i * 16 + r) * 32 + q * 8];
        #pragma unroll
        for (int i = 0; i < 4; ++i) bv[i] = *(const bf16x8*)&Bs[(wn + i * 16 + r) * 32 + q * 8];
        #pragma unroll
        for (int i = 0; i < 4; ++i)
            #pragma unroll
            for (int j = 0; j < 4; ++j)
                acc[i][j] = __builtin_amdgcn_mfma_f32_16x16x32_bf16(af[i], bv[j], acc[i][j], 0, 0, 0);
        __syncthreads();
    }

    #pragma unroll
    for (int i = 0; i < 4; ++i) {
        #pragma unroll
        for (int j = 0; j < 4; ++j) {
            #pragma unroll
            for (int g = 0; g < 4; ++g) {
                const int m = m0 + wm + i * 16 + q * 4 + g;
                const int n = n0 + wn + j * 16 + r;
                float v = acc[i][j][g];
                if (resid) v += resid[(long)m * ldr + n];
                if (outF)  outF[(long)m * ldf + n] = v;
                if (outB) {
                    if (vt && n >= 2048) {   // V section -> [b,h,p,s]
                        const int p = n - 2048, h = p >> 7, pp = p & 127;
                        const int b = m >> 9, s = m & 511;
                        vt[(((long)(b * 8 + h)) * 128 + pp) * 512 + s] = (__bf16)v;
                    } else {
                        outB[(long)m * ldo + n] = (__bf16)v;
                    }
                }
            }
        }
    }
}

// ---------------- fused causal attention: one-pass, S-resident ----------------
// Swapped-operand MFMA (S^T = mfma(K,Q), O^T = mfma(V,P)) so each lane owns one
// q-row with 4 consecutive k-cols per f32x4 -> float4 atts stores, bf16x4 comb
// stores, scalar per-lane softmax denom (2 shuffles). Heavy q-tiles dispatch
// first for causal load balance. No running max (|S*rs|<~2, shift -3 exact).
__global__ __launch_bounds__(256, 2) void flash2(
    const __bf16* __restrict__ QK, const __bf16* __restrict__ Vt,
    float* __restrict__ atts, __bf16* __restrict__ comb)
{
    const int f = blockIdx.x;
    const int bh = (f & 7) * 8 + ((f >> 3) & 7);   // XCD x gets batch b = x
    const int qt = 7 - (f >> 6);                   // heavy tiles first
    const int b = bh >> 3, h = bh & 7;
    const int nkt = (qt >> 1) + 1;                 // K tiles of 128 cols needed
    const float rs = 0.08838834764831845f;

    __shared__ __bf16 KVs[128 * 136];      // K in phase 1, V in phase 2
    __shared__ __bf16 Ps[4 * 16 * 136];    // per-wave P scratch (bf16)

    const int t = threadIdx.x, w = t >> 6, ln = t & 63;
    const int r = ln & 15, q = ln >> 4;

    // Q fragments (B-operand: col = ln&15 = q-row, k = (ln>>4)*8+j)
    const long qrow = (long)(b * 512 + qt * 64 + w * 16 + r);
    bf16x8 Qf[4];
    #pragma unroll
    for (int kp = 0; kp < 4; ++kp)
        Qf[kp] = *(const bf16x8*)(QK + qrow * 2048 + h * 128 + kp * 32 + q * 8);

    f16x4 E16[4][8];                       // exp(S*rs-3), packed f16, whole row
    float Lsum = 0.f;
    const int qr = qt * 64 + w * 16 + r;   // this lane's q-row (in-sequence)

    // ---- phase 1: S^T = K Q^T once; E = exp(S*rs - 3); accumulate row sum ----
    #pragma unroll
    for (int kt = 0; kt < 4; ++kt) {
        if (kt < nkt) {
            __syncthreads();
            const __bf16* ksrc = QK + ((long)(b * 512 + kt * 128)) * 2048 + 1024 + h * 128;
            #pragma unroll
            for (int c0 = 0; c0 < 8; ++c0) {
                const int c = c0 * 256 + t;
                const int row = c >> 4, col = (c & 15) * 8;
                *(bf16x8*)&KVs[row * 136 + col] = *(const bf16x8*)(ksrc + (long)row * 2048 + col);
            }
            __syncthreads();

            #pragma unroll
            for (int nb = 0; nb < 8; ++nb) {
                f32x4 s = f32x4{0.f, 0.f, 0.f, 0.f};
                #pragma unroll
                for (int kp = 0; kp < 4; ++kp) {
                    bf16x8 av = *(const bf16x8*)&KVs[(nb * 16 + r) * 136 + kp * 32 + q * 8];
                    s = __builtin_amdgcn_mfma_f32_16x16x32_bf16(av, Qf[kp], s, 0, 0, 0);
                }
                f16x4 e;
                #pragma unroll
                for (int g = 0; g < 4; ++g) {
                    float ev = __expf(s[g] * rs - 3.0f);
                    const int kc = kt * 128 + nb * 16 + q * 4 + g;
                    if (kt == nkt - 1 && kc > qr) ev = 0.f;
                    Lsum += ev;
                    e[g] = (_Float16)ev;
                }
                E16[kt][nb] = e;
            }
        }
    }

    // row denominator: this lane's row is spread over the 4 q-lane-groups
    Lsum += __shfl_xor(Lsum, 16);
    Lsum += __shfl_xor(Lsum, 32);
    const float linv = 1.0f / Lsum;

    f32x4 O[8];
    #pragma unroll
    for (int pb = 0; pb < 8; ++pb) O[pb] = f32x4{0.f, 0.f, 0.f, 0.f};

    float* arow = atts + (long)bh * 262144 + (long)qr * 512;
    __bf16* psw = &Ps[w * 16 * 136];

    // ---- phase 2: P = E * linv -> atts (float4) + Ps; O^T += V^T P ----
    #pragma unroll
    for (int kt = 0; kt < 4; ++kt) {
        if (kt < nkt) {
            __syncthreads();               // previous KVs readers done
            const __bf16* vsrc = Vt + (long)bh * 65536 + kt * 128;
            #pragma unroll
            for (int c0 = 0; c0 < 8; ++c0) {
                const int c = c0 * 256 + t;
                const int row = c >> 4, col = (c & 15) * 8;
                *(bf16x8*)&KVs[row * 136 + col] = *(const bf16x8*)(vsrc + (long)row * 512 + col);
            }
            __syncthreads();

            #pragma unroll
            for (int nb = 0; nb < 8; ++nb) {
                f16x4 e = E16[kt][nb];
                float4 pf4;
                bf16x4 pb4;
                #pragma unroll
                for (int g = 0; g < 4; ++g) {
                    float p = (float)e[g] * linv;
                    (&pf4.x)[g] = p;
                    pb4[g] = (__bf16)p;
                }
                *(float4*)&arow[kt * 128 + nb * 16 + q * 4] = pf4;
                *(bf16x4*)&psw[r * 136 + nb * 16 + q * 4] = pb4;
            }
            // PV: P rows are per-wave in Ps (intra-wave, no barrier needed)
            bf16x8 Pf[4];
            #pragma unroll
            for (int kp = 0; kp < 4; ++kp)
                Pf[kp] = *(const bf16x8*)&psw[r * 136 + kp * 32 + q * 8];
            #pragma unroll
            for (int pb = 0; pb < 8; ++pb) {
                #pragma unroll
                for (int kp = 0; kp < 4; ++kp) {
                    bf16x8 vv = *(const bf16x8*)&KVs[(pb * 16 + r) * 136 + kp * 32 + q * 8];
                    O[pb] = __builtin_amdgcn_mfma_f32_16x16x32_bf16(vv, Pf[kp], O[pb], 0, 0, 0);
                }
            }
        }
    }

    // zero-fill fully-masked tiles (exact per reference: exp underflow -> 0)
    {
        float* zbase = atts + (long)bh * 262144 + (long)(qt * 64) * 512;
        float4 z4 = {0.f, 0.f, 0.f, 0.f};
        for (int ktz = nkt; ktz < 4; ++ktz) {
            #pragma unroll
            for (int c0 = 0; c0 < 8; ++c0) {
                const int c = c0 * 256 + t;
                const int row = c >> 5, col = (c & 31) * 4;
                *(float4*)&zbase[(long)row * 512 + ktz * 128 + col] = z4;
            }
        }
    }

    // write O^T -> comb: lane owns q-row `qr`, 4 consecutive p per pb
    #pragma unroll
    for (int pb = 0; pb < 8; ++pb) {
        bf16x4 ob;
        #pragma unroll
        for (int g = 0; g < 4; ++g) ob[g] = (__bf16)O[pb][g];
        *(bf16x4*)&comb[qrow * 1024 + h * 128 + pb * 16 + q * 4] = ob;
    }
}

extern "C" void kernel_launch(void* const* d_in, const int* in_sizes, int n_in,
                              void* d_out, int out_size, void* d_ws, size_t ws_size,
                              hipStream_t stream)
{
    const float* tokens = (const float*)d_in[0];
    const float* embedW = (const float*)d_in[2];
    const float* unembW = (const float*)d_in[3];
    const float* wq     = (const float*)d_in[4];
    const float* wk     = (const float*)d_in[5];
    const float* wv     = (const float*)d_in[6];
    const float* wo     = (const float*)d_in[7];

    float* out       = (float*)d_out;
    float* logits_o  = out;                 // [8,512,256]
    float* atts_o    = out + 1048576L;      // [4,64,512,512]
    float* streams_o = atts_o + 67108864L;  // [5,4096,1024]

    __bf16* embedWt   = (__bf16*)d_ws;            // [1024][256]
    __bf16* unembWt   = embedWt + 262144;         // [256][1024]
    __bf16* WtAll     = unembWt + 262144;         // [L][3072][1024]
    __bf16* WotAll    = WtAll + 12582912;         // [L][1024][1024]
    __bf16* tokens_bf = WotAll + 4194304;         // [4096][256]
    __bf16* stream_bf = tokens_bf + 1048576;      // [4096][1024]
    __bf16* QKbuf     = stream_bf + 4194304;      // [4096][2048]
    __bf16* Vt        = QKbuf + 8388608;          // [64][128][512]
    __bf16* comb      = Vt + 4194304;             // [4096][1024]

    const dim3 T(32, 8), G1(256);

    // prep: token convert + all weight transposes (no interdependencies)
    cvt_bf16<<<dim3(1024), G1, 0, stream>>>(tokens, tokens_bf);
    transpose_cvt<<<dim3(32, 8, 1), T, 0, stream>>>(embedW, embedWt, 1024, 256, 0, 1, 0, 0);
    transpose_cvt<<<dim3(8, 32, 1), T, 0, stream>>>(unembW, unembWt, 256, 1024, 0, 1, 0, 0);
    transpose_qkv<<<dim3(4, 32, 96), T, 0, stream>>>(wq, wk, wv, WtAll);
    transpose_cvt<<<dim3(32, 32, 4), T, 0, stream>>>(wo, WotAll, 1024, 1024, 1048576, 1, 1048576, 0);

    // embed: [4096,256] x [256->1024]
    mfma_gemm<<<dim3(8, 32), G1, 0, stream>>>(
        tokens_bf, embedWt, 256, 256, 256,
        streams_o, 1024, stream_bf, 1024, nullptr, nullptr, 0);

    for (int l = 0; l < 4; ++l) {
        float* st  = streams_o + (long)l * 4194304;
        float* stn = st + 4194304;
        float* attl = atts_o + (long)l * 16777216;

        // QKV: [4096,1024] x [1024->3072]; q,k -> QKbuf, v -> Vt (transposed)
        mfma_gemm<<<dim3(24, 32), G1, 0, stream>>>(
            stream_bf, WtAll + (long)l * 3145728, 1024, 1024, 1024,
            nullptr, 0, QKbuf, 2048, Vt, nullptr, 0);

        flash2<<<dim3(512), G1, 0, stream>>>(QKbuf, Vt, attl, comb);

        // stream_{l+1} = stream_l + comb @ wo
        mfma_gemm<<<dim3(8, 32), G1, 0, stream>>>(
            comb, WotAll + (long)l * 1048576, 1024, 1024, 1024,
            stn, 1024, stream_bf, 1024, nullptr, st, 1024);
    }

    // logits = stream_L @ unembW
    mfma_gemm<<<dim3(2, 32), G1, 0, stream>>>(
        stream_bf, unembWt, 1024, 1024, 1024,
        logits_o, 256, nullptr, 0, nullptr, nullptr, 0);
}